// Round 1
// baseline (361.654 us; speedup 1.0000x reference)
//
#include <hip/hip_runtime.h>

#define BS 4
#define NF 8
#define NT 256
#define DIN 64
#define NH 8
#define DOUT 64

// ---------------------------------------------------------------------------
// Kernel A: query/key projections.
// query[b,f,t,h,e] = sum_d X[b,f,t,d] * W_query[f,t,d,h,e]   (same for key)
// One thread per output element (262144 total), 64-MAC dot each.
// ---------------------------------------------------------------------------
__global__ __launch_bounds__(256) void qk_kernel(
    const float* __restrict__ X,   // (BS,NF,NT,DIN)
    const float* __restrict__ Wq,  // (NF,NT,DIN,NH,2)
    const float* __restrict__ Wk,  // (NF,NT,DIN,NH,2)
    float* __restrict__ q,         // (BS,NF,NT,NH,2)
    float* __restrict__ k)         // (BS,NF,NT,NH,2)
{
    int idx = blockIdx.x * 256 + threadIdx.x;   // 0..262143
    int which = idx >> 17;                      // 0 = query, 1 = key
    int r = idx & ((1 << 17) - 1);              // ((b*NF+f)*NT+t)*16 + he
    int he = r & 15;
    int t  = (r >> 4) & 255;
    int f  = (r >> 12) & 7;
    int b  = r >> 15;

    const float* Wmat = which ? Wk : Wq;
    const float* xp = X + ((size_t)((b * NF + f) * NT + t) << 6);
    const float* wp = Wmat + ((size_t)(f * NT + t) << 10) + he;  // +d*16 steps

    float acc = 0.f;
    #pragma unroll 8
    for (int d = 0; d < DIN; ++d)
        acc = fmaf(xp[d], wp[d * 16], acc);

    float* outp = which ? k : q;
    outp[r] = acc;
}

// ---------------------------------------------------------------------------
// Kernel B: fused scores -> softmax -> probs@X -> @W + bias.
// One block (256 threads = 4 waves) per (b,f,t).
//
// score[h,l] = q[h,:]·key[l,h,:] + (q[h,:]+v[h,:])·rd[l,:] + u[l,:]·key_t[h,:]
//   rd[l,0] = Wk00*(l-t)^2 + Wk01*(l-t);  rd[l,1] = Wk10*(l-t)^2 + Wk11*(l-t)
//   v[h,0] = -alpha[f];  v[h,1] = 2*alpha[f]*attention_center[f,h]
// ---------------------------------------------------------------------------
__global__ __launch_bounds__(256) void attn_kernel(
    const float* __restrict__ X,      // (BS,NF,NT,DIN)
    const float* __restrict__ ac,     // (NF,NH,1)
    const float* __restrict__ alpha,  // (NF)
    const float* __restrict__ Wkey_,  // (NF,2,2)
    const float* __restrict__ u,      // (NF,NT,2)
    const float* __restrict__ W,      // (NF,NH*DIN,DOUT)
    const float* __restrict__ bias,   // (NF,NT,DOUT)
    const float* __restrict__ q,      // (BS,NF,NT,NH,2)
    const float* __restrict__ k,      // (BS,NF,NT,NH,2)
    float* __restrict__ out)          // (BS,NF,NT,DOUT)
{
    __shared__ float sS[NH][NT];        // scores -> probs (8 KB)
    __shared__ float sQ[NH][2];
    __shared__ float sKt[NH][2];
    __shared__ float sQV[NH][2];
    __shared__ float sV[NH * DIN];      // vals (2 KB)
    __shared__ float sPart[4][DOUT];    // epilogue partials (1 KB)

    const int tid = threadIdx.x;
    const int bid = blockIdx.x;         // t + NT*(f + NF*b)
    const int t = bid & 255;
    const int f = (bid >> 8) & 7;
    const int b = bid >> 11;
    const int bf = b * NF + f;

    const float* kbase = k + ((size_t)(bf * NT) << 4);  // key[b,f, l*16 + h*2+e]

    // ---- load q_t, key_t, build (q+v) --------------------------------------
    if (tid < 16) {
        int h = tid >> 1, e = tid & 1;
        float qv = q[((size_t)(bf * NT + t) << 4) + tid];
        float kt = kbase[((size_t)t << 4) + tid];
        sQ[h][e]  = qv;
        sKt[h][e] = kt;
        float al = alpha[f];
        float vv = (e == 0) ? (-al) : (2.f * al * ac[f * NH + h]);
        sQV[h][e] = qv + vv;
    }
    __syncthreads();

    // ---- scores: thread -> head h = tid>>5, 8 l's at stride 32 -------------
    {
        float wk0 = Wkey_[f * 4 + 0], wk1 = Wkey_[f * 4 + 1];
        float wk2 = Wkey_[f * 4 + 2], wk3 = Wkey_[f * 4 + 3];
        int h  = tid >> 5;
        int l0 = tid & 31;
        float q0 = sQ[h][0],  q1 = sQ[h][1];
        float a0 = sQV[h][0], a1 = sQV[h][1];
        float kt0 = sKt[h][0], kt1 = sKt[h][1];
        #pragma unroll
        for (int j = 0; j < 8; ++j) {
            int l = l0 + (j << 5);
            float rel = (float)(l - t);
            float r0 = rel * rel;
            float rd0 = fmaf(wk0, r0, wk1 * rel);
            float rd1 = fmaf(wk2, r0, wk3 * rel);
            float2 K = *(const float2*)(kbase + ((size_t)l << 4) + (h << 1));
            float2 U = *(const float2*)(u + (((f << 8) + l) << 1));
            float s = fmaf(q0, K.x, q1 * K.y);
            s = fmaf(a0, rd0, s);
            s = fmaf(a1, rd1, s);
            s = fmaf(U.x, kt0, s);
            s = fmaf(U.y, kt1, s);
            sS[h][l] = s;
        }
    }
    __syncthreads();

    // ---- softmax over l: wave w handles heads 2w, 2w+1 ---------------------
    {
        int wave = tid >> 6, lane = tid & 63;
        for (int hh = 0; hh < 2; ++hh) {
            int h = wave * 2 + hh;
            float v0 = sS[h][lane], v1 = sS[h][lane + 64];
            float v2 = sS[h][lane + 128], v3 = sS[h][lane + 192];
            float m = fmaxf(fmaxf(v0, v1), fmaxf(v2, v3));
            #pragma unroll
            for (int off = 32; off > 0; off >>= 1)
                m = fmaxf(m, __shfl_xor(m, off));
            float e0 = __expf(v0 - m), e1 = __expf(v1 - m);
            float e2 = __expf(v2 - m), e3 = __expf(v3 - m);
            float s = (e0 + e1) + (e2 + e3);
            #pragma unroll
            for (int off = 32; off > 0; off >>= 1)
                s += __shfl_xor(s, off);
            float inv = 1.f / s;
            sS[h][lane]       = e0 * inv;
            sS[h][lane + 64]  = e1 * inv;
            sS[h][lane + 128] = e2 * inv;
            sS[h][lane + 192] = e3 * inv;
        }
    }
    __syncthreads();

    // ---- vals[h,d] = sum_l probs[h,l] * X[b,f,l,d] -------------------------
    // thread: h = tid>>5, d-pair = (tid&31)*2 ; float2 X loads
    {
        int h  = tid >> 5;
        int d2 = (tid & 31) << 1;
        const float* xbase = X + ((size_t)(bf * NT) << 6) + d2;
        float ax = 0.f, ay = 0.f;
        #pragma unroll 4
        for (int l = 0; l < NT; ++l) {
            float2 xv = *(const float2*)(xbase + (l << 6));
            float p = sS[h][l];
            ax = fmaf(p, xv.x, ax);
            ay = fmaf(p, xv.y, ay);
        }
        sV[(h << 6) + d2]     = ax;
        sV[(h << 6) + d2 + 1] = ay;
    }
    __syncthreads();

    // ---- out[o] = sum_k sV[k] * W[f,k,o] + bias[f,t,o] ---------------------
    {
        int o = tid & 63, part = tid >> 6;
        const float* wbase = W + ((size_t)f << 15) + o;  // f*512*64
        int k0 = part << 7;
        float acc = 0.f;
        #pragma unroll 8
        for (int kk = 0; kk < 128; ++kk)
            acc = fmaf(sV[k0 + kk], wbase[(size_t)(k0 + kk) << 6], acc);
        sPart[part][o] = acc;
    }
    __syncthreads();
    if (tid < 64) {
        float r = (sPart[0][tid] + sPart[1][tid]) + (sPart[2][tid] + sPart[3][tid]);
        r += bias[(((f << 8) + t) << 6) + tid];
        out[(((size_t)(bf * NT) + t) << 6) + tid] = r;
    }
}

extern "C" void kernel_launch(void* const* d_in, const int* in_sizes, int n_in,
                              void* d_out, int out_size, void* d_ws, size_t ws_size,
                              hipStream_t stream) {
    const float* X     = (const float*)d_in[0];
    const float* ac    = (const float*)d_in[1];
    const float* alpha = (const float*)d_in[2];
    const float* Wq    = (const float*)d_in[3];
    const float* Wk    = (const float*)d_in[4];
    const float* Wkey_ = (const float*)d_in[5];
    const float* u     = (const float*)d_in[6];
    const float* W     = (const float*)d_in[7];
    const float* bb    = (const float*)d_in[8];
    float* out = (float*)d_out;

    float* q = (float*)d_ws;          // BS*NF*NT*NH*2 = 131072 floats
    float* k = q + (BS * NF * NT * NH * 2);

    hipLaunchKernelGGL(qk_kernel, dim3(2 * BS * NF * NT * NH * 2 / 256), dim3(256), 0, stream,
                       X, Wq, Wk, q, k);
    hipLaunchKernelGGL(attn_kernel, dim3(BS * NF * NT), dim3(256), 0, stream,
                       X, ac, alpha, Wkey_, u, W, bb, q, k, out);
}

// Round 2
// 154.187 us; speedup vs baseline: 2.3456x; 2.3456x over previous
//
#include <hip/hip_runtime.h>

#define BS 4
#define NF 8
#define NT 256
#define DIN 64
#define NH 8
#define DOUT 64

// ---------------------------------------------------------------------------
// Kernel A: query/key projections, one block per (f,t).
// query[b,f,t,h,e] = sum_d X[b,f,t,d] * W_query[f,t,d,h,e]   (same for key)
// Stage W_q/W_k tile (2048 floats) + X rows (256 floats) in LDS, coalesced.
// 128 outputs (b x which x he), 2 threads per output (d split), shfl combine.
// ---------------------------------------------------------------------------
__global__ __launch_bounds__(256) void qk_kernel(
    const float* __restrict__ X,   // (BS,NF,NT,DIN)
    const float* __restrict__ Wq,  // (NF,NT,DIN,NH,2)
    const float* __restrict__ Wk,  // (NF,NT,DIN,NH,2)
    float* __restrict__ q,         // (BS,NF,NT,NH,2)
    float* __restrict__ k)         // (BS,NF,NT,NH,2)
{
    __shared__ float sW[2048];     // [which*1024 + d*16 + he]
    __shared__ float sX[4 * 64];   // [b*64 + d]

    const int tid = threadIdx.x;
    const int ft = blockIdx.x;     // f*NT + t
    const int f = ft >> 8, t = ft & 255;

    const float4* wq4 = (const float4*)(Wq + ((size_t)ft << 10));
    const float4* wk4 = (const float4*)(Wk + ((size_t)ft << 10));
    ((float4*)sW)[tid]       = wq4[tid];
    ((float4*)sW)[256 + tid] = wk4[tid];
    {
        int b = tid >> 6, d = tid & 63;
        sX[tid] = X[(((size_t)((b * NF + f) * NT + t)) << 6) + d];
    }
    __syncthreads();

    const int outi  = tid >> 1;
    const int half  = tid & 1;
    const int b     = outi >> 5;
    const int which = (outi >> 4) & 1;
    const int he    = outi & 15;

    const float* xp = sX + (b << 6) + (half << 5);
    const float* wp = sW + which * 1024 + (half << 9) + he;  // half*32*16
    float acc = 0.f;
    #pragma unroll
    for (int d = 0; d < 32; ++d)
        acc = fmaf(xp[d], wp[d << 4], acc);
    acc += __shfl_xor(acc, 1);

    if (half == 0) {
        float* outp = which ? k : q;
        outp[(((size_t)((b * NF + f) * NT + t)) << 4) + he] = acc;
    }
}

// ---------------------------------------------------------------------------
// Kernel B: fused scores -> softmax -> probs@X -> @W + bias.
// One block (256 threads = 4 waves) per (b,f,t).
// ---------------------------------------------------------------------------
__global__ __launch_bounds__(256) void attn_kernel(
    const float* __restrict__ X,      // (BS,NF,NT,DIN)
    const float* __restrict__ ac,     // (NF,NH,1)
    const float* __restrict__ alpha,  // (NF)
    const float* __restrict__ Wkey_,  // (NF,2,2)
    const float* __restrict__ u,      // (NF,NT,2)
    const float* __restrict__ W,      // (NF,NH*DIN,DOUT)
    const float* __restrict__ bias,   // (NF,NT,DOUT)
    const float* __restrict__ q,      // (BS,NF,NT,NH,2)
    const float* __restrict__ kk,     // (BS,NF,NT,NH,2)
    float* __restrict__ out)          // (BS,NF,NT,DOUT)
{
    // sBuf phases: probs[l*8+h] (8KB) -> vals partials [lq*512+h*64+d]
    //           -> epilogue partials [kp*64+o]. Barrier-separated reuse.
    __shared__ float sBuf[2048];
    __shared__ float sV[512];            // vals[h*64+d]
    __shared__ float sQ[16], sKt[16], sQV[16];
    __shared__ float sWm[4][8], sWs[4][8];

    const int tid = threadIdx.x;
    const int bid = blockIdx.x;          // t + NT*(f + NF*b)
    const int t = bid & 255;
    const int f = (bid >> 8) & 7;
    const int b = bid >> 11;
    const int bf = b * NF + f;

    const float* kbase = kk + ((size_t)(bf * NT) << 4);

    // ---- tiny init: q_t, key_t, q+v ----------------------------------------
    if (tid < 16) {
        int h = tid >> 1, e = tid & 1;
        float qv = q[((size_t)(bf * NT + t) << 4) + tid];
        float kt = kbase[((size_t)t << 4) + tid];
        sQ[tid]  = qv;
        sKt[tid] = kt;
        float al = alpha[f];
        float vv = (e == 0) ? (-al) : (2.f * al * ac[f * NH + h]);
        sQV[tid] = qv + vv;
    }
    __syncthreads();

    // ---- phase 1: scores, kept in registers --------------------------------
    const int h    = tid & 7;
    const int lrow = tid >> 3;           // 0..31
    float s[8];
    {
        float wk0 = Wkey_[f * 4 + 0], wk1 = Wkey_[f * 4 + 1];
        float wk2 = Wkey_[f * 4 + 2], wk3 = Wkey_[f * 4 + 3];
        float q0 = sQ[h * 2],  q1 = sQ[h * 2 + 1];
        float a0 = sQV[h * 2], a1 = sQV[h * 2 + 1];
        float kt0 = sKt[h * 2], kt1 = sKt[h * 2 + 1];
        #pragma unroll
        for (int j = 0; j < 8; ++j) {
            int l = lrow + (j << 5);
            float rel = (float)(l - t);
            float r2 = rel * rel;
            float rd0 = fmaf(wk0, r2, wk1 * rel);
            float rd1 = fmaf(wk2, r2, wk3 * rel);
            float2 K = *(const float2*)(kbase + ((size_t)l << 4) + (h << 1));
            float2 U = *(const float2*)(u + ((size_t)((f << 8) + l) << 1));
            float sc = fmaf(q0, K.x, q1 * K.y);
            sc = fmaf(a0, rd0, sc);
            sc = fmaf(a1, rd1, sc);
            sc = fmaf(U.x, kt0, sc);
            sc = fmaf(U.y, kt1, sc);
            s[j] = sc;
        }
    }

    // ---- phase 2: softmax over l (regs + shfl + tiny LDS cross-wave) -------
    const int wave = tid >> 6;
    {
        float m = s[0];
        #pragma unroll
        for (int j = 1; j < 8; ++j) m = fmaxf(m, s[j]);
        m = fmaxf(m, __shfl_xor(m, 8));
        m = fmaxf(m, __shfl_xor(m, 16));
        m = fmaxf(m, __shfl_xor(m, 32));
        if ((tid & 63) < 8) sWm[wave][h] = m;
    }
    __syncthreads();
    {
        float M = fmaxf(fmaxf(sWm[0][h], sWm[1][h]), fmaxf(sWm[2][h], sWm[3][h]));
        float ssum = 0.f;
        #pragma unroll
        for (int j = 0; j < 8; ++j) { s[j] = __expf(s[j] - M); ssum += s[j]; }
        ssum += __shfl_xor(ssum, 8);
        ssum += __shfl_xor(ssum, 16);
        ssum += __shfl_xor(ssum, 32);
        if ((tid & 63) < 8) sWs[wave][h] = ssum;
    }
    __syncthreads();
    {
        float S = (sWs[0][h] + sWs[1][h]) + (sWs[2][h] + sWs[3][h]);
        float inv = 1.f / S;
        #pragma unroll
        for (int j = 0; j < 8; ++j)
            sBuf[((lrow + (j << 5)) << 3) + h] = s[j] * inv;  // probs, [l][h]
    }
    __syncthreads();

    // ---- phase 3: vals[h,d] = sum_l p[l,h] * X[l,d] ------------------------
    // thread = (lq = wave, d); wave-uniform l -> broadcast ds_read_b128 of p
    {
        const int d = tid & 63;
        float acc[8] = {0.f, 0.f, 0.f, 0.f, 0.f, 0.f, 0.f, 0.f};
        const float* xb = X + (((size_t)(bf * NT)) << 6) + d;
        const int lbase = wave << 6;
        #pragma unroll 4
        for (int j = 0; j < 64; ++j) {
            int l = lbase + j;
            float x = xb[(size_t)l << 6];
            float4 pa = *(const float4*)&sBuf[l << 3];
            float4 pb = *(const float4*)&sBuf[(l << 3) + 4];
            acc[0] = fmaf(pa.x, x, acc[0]);
            acc[1] = fmaf(pa.y, x, acc[1]);
            acc[2] = fmaf(pa.z, x, acc[2]);
            acc[3] = fmaf(pa.w, x, acc[3]);
            acc[4] = fmaf(pb.x, x, acc[4]);
            acc[5] = fmaf(pb.y, x, acc[5]);
            acc[6] = fmaf(pb.z, x, acc[6]);
            acc[7] = fmaf(pb.w, x, acc[7]);
        }
        __syncthreads();                     // all probs reads done
        #pragma unroll
        for (int hh = 0; hh < 8; ++hh)
            sBuf[(wave << 9) + (hh << 6) + d] = acc[hh];
    }
    __syncthreads();
    {
        int i0 = tid, i1 = tid + 256;
        sV[i0] = (sBuf[i0] + sBuf[512 + i0]) + (sBuf[1024 + i0] + sBuf[1536 + i0]);
        sV[i1] = (sBuf[i1] + sBuf[512 + i1]) + (sBuf[1024 + i1] + sBuf[1536 + i1]);
    }
    __syncthreads();

    // ---- phase 4: out[o] = sum_k sV[k]*W[f,k,o] + bias ---------------------
    // thread = (kp 0..15, o-quad); float4 W loads, sV broadcast
    {
        const int kp = tid >> 4;
        const int o4 = (tid & 15) << 2;
        const float* wb = W + ((size_t)f << 15) + (((size_t)kp << 5) << 6) + o4;
        float4 a4 = {0.f, 0.f, 0.f, 0.f};
        #pragma unroll 4
        for (int i = 0; i < 32; ++i) {
            float v = sV[(kp << 5) + i];
            float4 w4 = *(const float4*)(wb + ((size_t)i << 6));
            a4.x = fmaf(v, w4.x, a4.x);
            a4.y = fmaf(v, w4.y, a4.y);
            a4.z = fmaf(v, w4.z, a4.z);
            a4.w = fmaf(v, w4.w, a4.w);
        }
        *(float4*)&sBuf[(kp << 6) + o4] = a4;   // safe: sBuf reads ended at barrier above
    }
    __syncthreads();
    if (tid < 64) {
        float r = 0.f;
        #pragma unroll
        for (int p = 0; p < 16; ++p) r += sBuf[(p << 6) + tid];
        r += bias[((size_t)((f << 8) + t) << 6) + tid];
        out[(((size_t)(bf * NT) + t) << 6) + tid] = r;
    }
}

extern "C" void kernel_launch(void* const* d_in, const int* in_sizes, int n_in,
                              void* d_out, int out_size, void* d_ws, size_t ws_size,
                              hipStream_t stream) {
    const float* X     = (const float*)d_in[0];
    const float* ac    = (const float*)d_in[1];
    const float* alpha = (const float*)d_in[2];
    const float* Wq    = (const float*)d_in[3];
    const float* Wk    = (const float*)d_in[4];
    const float* Wkey_ = (const float*)d_in[5];
    const float* u     = (const float*)d_in[6];
    const float* W     = (const float*)d_in[7];
    const float* bb    = (const float*)d_in[8];
    float* out = (float*)d_out;

    float* q = (float*)d_ws;          // BS*NF*NT*NH*2 = 65536 floats
    float* k = q + (BS * NF * NT * NH * 2);

    hipLaunchKernelGGL(qk_kernel, dim3(NF * NT), dim3(256), 0, stream,
                       X, Wq, Wk, q, k);
    hipLaunchKernelGGL(attn_kernel, dim3(BS * NF * NT), dim3(256), 0, stream,
                       X, ac, alpha, Wkey_, u, W, bb, q, k, out);
}

// Round 3
// 120.835 us; speedup vs baseline: 2.9930x; 1.2760x over previous
//
#include <hip/hip_runtime.h>
#include <hip/hip_bf16.h>

#define BS 4
#define NF 8
#define NT 256
#define DIN 64
#define NH 8
#define DOUT 64
#define TT 8          // t's per attn block
#define MROWS 64      // TT*NH score rows per block
#define NCHUNK 32     // NT/TT

typedef unsigned short u16;
typedef __attribute__((ext_vector_type(8))) short short8;
typedef __attribute__((ext_vector_type(4))) float f32x4;
typedef __attribute__((ext_vector_type(4))) unsigned int u32x4;

static __device__ __forceinline__ u16 f2bf(float x) {
    __hip_bfloat16 h = __float2bfloat16(x);
    u16 r; __builtin_memcpy(&r, &h, 2); return r;
}
static __device__ __forceinline__ unsigned pk2(float a, float b) {
    return (unsigned)f2bf(a) | ((unsigned)f2bf(b) << 16);
}

// ---------------------------------------------------------------------------
// prep: [0,2048) qk projections ; [2048,2080) X -> XT bf16 [bf][d][l]
//       [2080,2144) W -> Wt bf16 [f][o][kk]
// ---------------------------------------------------------------------------
__global__ __launch_bounds__(256) void prep_kernel(
    const float* __restrict__ X,
    const float* __restrict__ Wq,
    const float* __restrict__ Wk,
    const float* __restrict__ W,
    float* __restrict__ q,
    float* __restrict__ k,
    u16* __restrict__ XT,
    u16* __restrict__ Wt)
{
    __shared__ float sW[2048];
    __shared__ float sX[256];
    __shared__ float sT[64][65];
    const int tid = threadIdx.x;
    const int bid = blockIdx.x;

    if (bid < 2048) {
        const int ft = bid;                  // f*NT + t
        const int f = ft >> 8, t = ft & 255;
        const float4* wq4 = (const float4*)(Wq + ((size_t)ft << 10));
        const float4* wk4 = (const float4*)(Wk + ((size_t)ft << 10));
        ((float4*)sW)[tid]       = wq4[tid];
        ((float4*)sW)[256 + tid] = wk4[tid];
        {
            int b = tid >> 6, d = tid & 63;
            sX[tid] = X[(((size_t)((b * NF + f) * NT + t)) << 6) + d];
        }
        __syncthreads();
        const int outi  = tid >> 1;
        const int half  = tid & 1;
        const int b     = outi >> 5;
        const int which = (outi >> 4) & 1;
        const int he    = outi & 15;
        const float* xp = sX + (b << 6) + (half << 5);
        const float* wp = sW + which * 1024 + (half << 9) + he;
        float acc = 0.f;
        #pragma unroll
        for (int d = 0; d < 32; ++d)
            acc = fmaf(xp[d], wp[d << 4], acc);
        acc += __shfl_xor(acc, 1);
        if (half == 0) {
            float* outp = which ? k : q;
            outp[(((size_t)((b * NF + f) * NT + t)) << 4) + he] = acc;
        }
    } else if (bid < 2080) {
        const int bf = bid - 2048;
        for (int lc = 0; lc < 4; ++lc) {
            #pragma unroll
            for (int i = 0; i < 16; ++i) {
                int l = i * 4 + (tid >> 6), d = tid & 63;
                sT[l][d] = X[(((size_t)(bf * NT) + lc * 64 + l) << 6) + d];
            }
            __syncthreads();
            #pragma unroll
            for (int i = 0; i < 16; ++i) {
                int d = i * 4 + (tid >> 6), l = tid & 63;
                XT[(((size_t)(bf * 64) + d) << 8) + lc * 64 + l] = f2bf(sT[l][d]);
            }
            __syncthreads();
        }
    } else {
        const int idx = bid - 2080;
        const int f = idx >> 3, kc = idx & 7;
        #pragma unroll
        for (int i = 0; i < 16; ++i) {
            int kk = i * 4 + (tid >> 6), o = tid & 63;
            sT[kk][o] = W[(((size_t)(f * 512) + kc * 64 + kk) << 6) + o];
        }
        __syncthreads();
        #pragma unroll
        for (int i = 0; i < 16; ++i) {
            int o = i * 4 + (tid >> 6), kk = tid & 63;
            Wt[(((size_t)(f * 64) + o) << 9) + kc * 64 + kk] = f2bf(sT[kk][o]);
        }
    }
}

// ---------------------------------------------------------------------------
// attn: block = (b, f, 8-t chunk). Scores fp32 VALU (2-pass softmax) ->
// P bf16 in LDS (swizzled A-layout) -> MFMA P@X -> MFMA vals@W -> out.
// ---------------------------------------------------------------------------
__global__ __launch_bounds__(256, 2) void attn_kernel(
    const float* __restrict__ ac,
    const float* __restrict__ alpha,
    const float* __restrict__ Wkey_,
    const float* __restrict__ u,
    const float* __restrict__ bias,
    const float* __restrict__ q,
    const float* __restrict__ kws,
    const u16* __restrict__ XT,
    const u16* __restrict__ Wt,
    float* __restrict__ out)
{
    __shared__ u16  sP[MROWS * 256];   // 32 KB, chunk^=(m&15) swizzle
    __shared__ float sKU[4608];        // sK[256][16]+sU[256][2]; reused as sVals u16[16][520]
    __shared__ float sC[MROWS * 8];
    __shared__ float sRed[4 * MROWS];
    __shared__ float sInvS[MROWS];

    const int tid = threadIdx.x;
    const int bid = blockIdx.x;
    const int ch = bid & 31;
    const int f  = (bid >> 5) & 7;
    const int b  = bid >> 8;
    const int bf = b * NF + f;
    const int t0 = ch * TT;

    // ---- stage K (fp32) and U ----
    {
        const float4* k4 = (const float4*)(kws + ((size_t)bf << 12));
        float4* d4 = (float4*)sKU;
        #pragma unroll
        for (int i = 0; i < 4; ++i) d4[i * 256 + tid] = k4[i * 256 + tid];
        if (tid < 128) ((float4*)(sKU + 4096))[tid] = ((const float4*)(u + f * 512))[tid];
    }
    __syncthreads();
    // ---- per-row constants ----
    if (tid < MROWS) {
        int m = tid, h = m & 7, t = t0 + (m >> 3);
        float q0 = q[((size_t)(bf * NT + t) << 4) + h * 2];
        float q1 = q[((size_t)(bf * NT + t) << 4) + h * 2 + 1];
        float kt0 = sKU[t * 16 + h * 2], kt1 = sKU[t * 16 + h * 2 + 1];
        float al = alpha[f];
        float a0 = q0 - al;
        float a1 = q1 + 2.f * al * ac[f * 8 + h];
        float wk0 = Wkey_[f * 4], wk1 = Wkey_[f * 4 + 1];
        float wk2 = Wkey_[f * 4 + 2], wk3 = Wkey_[f * 4 + 3];
        float* cc = sC + m * 8;
        cc[0] = q0; cc[1] = q1; cc[2] = kt0; cc[3] = kt1;
        cc[4] = a0 * wk0 + a1 * wk2;   // c2
        cc[5] = a0 * wk1 + a1 * wk3;   // c1
    }
    __syncthreads();

    const int m  = tid & 63;
    const int lq = tid >> 6;
    const int t  = t0 + (m >> 3);
    const int h  = m & 7;
    float q0, q1, kt0, kt1, c2, c1;
    {
        const float* cc = sC + m * 8;
        q0 = cc[0]; q1 = cc[1]; kt0 = cc[2]; kt1 = cc[3]; c2 = cc[4]; c1 = cc[5];
    }
    const float* sKp = sKU;
    const float* sUp = sKU + 4096;

    // ---- pass A: max ----
    float mx = -1e30f;
    {
        float rel = (float)(lq * 64 - t);
        #pragma unroll 8
        for (int j = 0; j < 64; ++j) {
            int l = lq * 64 + j;
            float2 K = *(const float2*)(sKp + l * 16 + h * 2);
            float2 U = *(const float2*)(sUp + l * 2);
            float s = (c2 * rel + c1) * rel;
            s = fmaf(q0, K.x, s); s = fmaf(q1, K.y, s);
            s = fmaf(kt0, U.x, s); s = fmaf(kt1, U.y, s);
            mx = fmaxf(mx, s);
            rel += 1.f;
        }
    }
    sRed[lq * 64 + m] = mx;
    __syncthreads();
    const float M = fmaxf(fmaxf(sRed[m], sRed[64 + m]), fmaxf(sRed[128 + m], sRed[192 + m]));
    __syncthreads();

    // ---- pass B: exp, sum, write P (bf16, unnormalized) ----
    float sum = 0.f;
    {
        float rel = (float)(lq * 64 - t);
        unsigned pk[4]; float ep = 0.f;
        #pragma unroll 8
        for (int j = 0; j < 64; ++j) {
            int l = lq * 64 + j;
            float2 K = *(const float2*)(sKp + l * 16 + h * 2);
            float2 U = *(const float2*)(sUp + l * 2);
            float s = (c2 * rel + c1) * rel;
            s = fmaf(q0, K.x, s); s = fmaf(q1, K.y, s);
            s = fmaf(kt0, U.x, s); s = fmaf(kt1, U.y, s);
            float e = __expf(s - M);
            sum += e;
            if ((j & 1) == 0) ep = e;
            else pk[(j & 7) >> 1] = pk2(ep, e);
            if ((j & 7) == 7) {
                int chunk = l >> 3;
                int phys = chunk ^ (m & 15);
                *(u32x4*)&sP[m * 256 + phys * 8] = (u32x4){pk[0], pk[1], pk[2], pk[3]};
            }
            rel += 1.f;
        }
    }
    sRed[lq * 64 + m] = sum;
    __syncthreads();
    if (tid < MROWS)
        sInvS[tid] = 1.f / ((sRed[tid] + sRed[64 + tid]) + (sRed[128 + tid] + sRed[192 + tid]));
    __syncthreads();

    // ---- phase 3: vals = P @ X via MFMA (M=64, K=256, N=64) ----
    const int wv   = tid >> 6;
    const int lane = tid & 63;
    const int quad = lane >> 4;
    const int ln   = lane & 15;

    f32x4 acc0 = {0.f, 0.f, 0.f, 0.f}, acc1 = acc0, acc2 = acc0, acc3 = acc0;
    const u16* xb = XT + ((size_t)bf << 14);
    #pragma unroll
    for (int ks = 0; ks < 8; ++ks) {
        int chunk = ks * 4 + quad;
        int phys = chunk ^ ln;
        short8 a = *(const short8*)&sP[(wv * 16 + ln) * 256 + phys * 8];
        int l = ks * 32 + quad * 8;
        short8 b0 = *(const short8*)(xb + (0 * 16 + ln) * 256 + l);
        short8 b1 = *(const short8*)(xb + (1 * 16 + ln) * 256 + l);
        short8 b2 = *(const short8*)(xb + (2 * 16 + ln) * 256 + l);
        short8 b3 = *(const short8*)(xb + (3 * 16 + ln) * 256 + l);
        acc0 = __builtin_amdgcn_mfma_f32_16x16x32_bf16(a, b0, acc0, 0, 0, 0);
        acc1 = __builtin_amdgcn_mfma_f32_16x16x32_bf16(a, b1, acc1, 0, 0, 0);
        acc2 = __builtin_amdgcn_mfma_f32_16x16x32_bf16(a, b2, acc2, 0, 0, 0);
        ac3:;
        acc3 = __builtin_amdgcn_mfma_f32_16x16x32_bf16(a, b3, acc3, 0, 0, 0);
    }

    u16* sVals = (u16*)sKU;   // [t][520]
    #pragma unroll
    for (int reg = 0; reg < 4; ++reg) {
        int mg = wv * 16 + quad * 4 + reg;
        float inv = sInvS[mg];
        int tl = mg >> 3, hh = mg & 7;
        u16* dst = sVals + tl * 520 + hh * 64 + ln;
        dst[0]  = f2bf(acc0[reg] * inv);
        dst[16] = f2bf(acc1[reg] * inv);
        dst[32] = f2bf(acc2[reg] * inv);
        dst[48] = f2bf(acc3[reg] * inv);
    }
    __syncthreads();

    // ---- phase 4: out = vals @ W via MFMA (M=8(pad16), K=512, N=64) ----
    f32x4 oacc = {0.f, 0.f, 0.f, 0.f};
    const u16* wb = Wt + ((size_t)(f * 64 + wv * 16 + ln) << 9);
    #pragma unroll
    for (int ks = 0; ks < 16; ++ks) {
        int k2 = ks * 32 + quad * 8;
        short8 a = *(const short8*)(sVals + ln * 520 + k2);
        short8 bw = *(const short8*)(wb + k2);
        oacc = __builtin_amdgcn_mfma_f32_16x16x32_bf16(a, bw, oacc, 0, 0, 0);
    }
    {
        int o = wv * 16 + ln;
        #pragma unroll
        for (int reg = 0; reg < 4; ++reg) {
            int tl = quad * 4 + reg;
            if (tl < TT) {
                int tg = t0 + tl;
                out[((size_t)(bf * NT + tg) << 6) + o] =
                    oacc[reg] + bias[((size_t)(f * NT + tg) << 6) + o];
            }
        }
    }
}

extern "C" void kernel_launch(void* const* d_in, const int* in_sizes, int n_in,
                              void* d_out, int out_size, void* d_ws, size_t ws_size,
                              hipStream_t stream) {
    const float* X     = (const float*)d_in[0];
    const float* ac    = (const float*)d_in[1];
    const float* alpha = (const float*)d_in[2];
    const float* Wq    = (const float*)d_in[3];
    const float* Wk    = (const float*)d_in[4];
    const float* Wkey_ = (const float*)d_in[5];
    const float* u     = (const float*)d_in[6];
    const float* W     = (const float*)d_in[7];
    const float* bb    = (const float*)d_in[8];
    float* out = (float*)d_out;

    float* qws = (float*)d_ws;                  // 131072 f
    float* kws = qws + 131072;                  // 131072 f
    u16* XT = (u16*)(kws + 131072);             // 524288 u16
    u16* Wt = XT + 524288;                      // 262144 u16

    hipLaunchKernelGGL(prep_kernel, dim3(2144), dim3(256), 0, stream,
                       X, Wq, Wk, W, qws, kws, XT, Wt);
    hipLaunchKernelGGL(attn_kernel, dim3(BS * NF * NCHUNK), dim3(256), 0, stream,
                       ac, alpha, Wkey_, u, bb, qws, kws, XT, Wt, out);
}